// Round 5
// baseline (692.400 us; speedup 1.0000x reference)
//
#include <hip/hip_runtime.h>
#include <math.h>

// ---------------------------------------------------------------------------
// GPT transformer block, internal bf16 compute / fp32 accumulate.
// B=4, T=2048, D=1024 (8192 rows), 3D=3072, 4D=4096.
// Round 5: BK=32 (round-3 structure, measured faster than BK=64), pair-
// swizzled LDS (q ^ ((r>>1)&3)) -> conflict-free b128 reads while keeping
// global_load_lds wave-contiguous dest; fast GELU via __expf+rcp (the round-3/4
// FC epilogue burned ~50us/CU in libm tanhf); bf16 scores.
// ---------------------------------------------------------------------------

typedef unsigned short u16;
typedef __attribute__((ext_vector_type(8))) short bf16x8;   // 8 bf16 = 4 VGPRs
typedef __attribute__((ext_vector_type(4))) float f32x4;

#define DEV __device__ __forceinline__

#define GLOAD_LDS16(gp, lp)                                                     \
    __builtin_amdgcn_global_load_lds(                                           \
        (const __attribute__((address_space(1))) void*)(gp),                    \
        (__attribute__((address_space(3))) void*)(lp), 16, 0, 0)

DEV float bf2f(u16 h) {
    union { unsigned u; float f; } t; t.u = ((unsigned)h) << 16; return t.f;
}
DEV u16 f2bf(float f) {
    union { unsigned u; float f; } t; t.f = f;
    unsigned u = t.u;
    return (u16)((u + 0x7FFFu + ((u >> 16) & 1u)) >> 16);   // round-nearest-even
}
DEV float loadIn(const void* p, long i, int isbf) {
    return isbf ? bf2f(((const u16*)p)[i]) : ((const float*)p)[i];
}
// gelu(x) = 0.5x(1+tanh(u)) = x * sigmoid(2u); ~6 VALU vs libm tanhf's ~30+
DEV float gelu_fast(float x) {
    float u = 1.5957691216057308f * (x + 0.044715f * x * x * x);  // 2*sqrt(2/pi)
    return x * __builtin_amdgcn_rcpf(1.0f + __expf(-u));
}

DEV float waveSum(float v) {
    #pragma unroll
    for (int o = 32; o > 0; o >>= 1) v += __shfl_down(v, o, 64);
    return v;
}
DEV float waveMax(float v) {
    #pragma unroll
    for (int o = 32; o > 0; o >>= 1) v = fmaxf(v, __shfl_down(v, o, 64));
    return v;
}

template <bool IS_MAX>
DEV float blockReduce(float v) {
    __shared__ float tmp[5];
    __syncthreads();
    v = IS_MAX ? waveMax(v) : waveSum(v);
    int lane = threadIdx.x & 63, w = threadIdx.x >> 6;
    if (lane == 0) tmp[w] = v;
    __syncthreads();
    if (threadIdx.x == 0) {
        float r = tmp[0];
        for (int i = 1; i < 4; i++) r = IS_MAX ? fmaxf(r, tmp[i]) : (r + tmp[i]);
        tmp[4] = r;
    }
    __syncthreads();
    return tmp[4];
}

// ---------------- dtype detection (1 block) --------------------------------
__global__ void detect_dtype(const u16* __restrict__ xr, int* __restrict__ flag) {
    const int tid = threadIdx.x;           // 256
    int cnt = 0;
    #pragma unroll
    for (int i = 0; i < 16; i++) {
        unsigned u = xr[2 * (tid + 256 * i)];      // even u16 indices
        unsigned e = (u >> 7) & 0xFF;              // bf16 exponent field
        cnt += (e >= 100 && e <= 140) ? 1 : 0;     // ~always for bf16 N(0,1)
    }
    __shared__ int sh[4];
    #pragma unroll
    for (int o = 32; o > 0; o >>= 1) cnt += __shfl_down(cnt, o, 64);
    if ((tid & 63) == 0) sh[tid >> 6] = cnt;
    __syncthreads();
    if (tid == 0) flag[0] = (sh[0] + sh[1] + sh[2] + sh[3] > 2048) ? 1 : 0;
}

// ---------------- LayerNorm (D=1024, one 256-thread block per row) ---------
template <bool RAW_IN>
__global__ void ln_kernel(const void* __restrict__ x, const void* __restrict__ g,
                          const void* __restrict__ b, u16* __restrict__ out,
                          const int* __restrict__ flagp) {
    const int isbf = *flagp;
    const int inbf = RAW_IN ? isbf : 1;
    const long base = (long)blockIdx.x * 1024;
    const int tid = threadIdx.x;
    float v[4];
    #pragma unroll
    for (int j = 0; j < 4; j++) v[j] = loadIn(x, base + tid + 256 * j, inbf);
    float mu = blockReduce<false>(v[0] + v[1] + v[2] + v[3]) * (1.0f / 1024.0f);
    float d[4], sq = 0.f;
    #pragma unroll
    for (int j = 0; j < 4; j++) { d[j] = v[j] - mu; sq += d[j] * d[j]; }
    float var = blockReduce<false>(sq) * (1.0f / 1024.0f);
    float rstd = rsqrtf(var + 1e-5f);
    #pragma unroll
    for (int j = 0; j < 4; j++) {
        int c = tid + 256 * j;
        out[base + c] = f2bf(d[j] * rstd * loadIn(g, c, isbf) + loadIn(b, c, isbf));
    }
}

// ---------------- 32x32 transpose -> bf16 ----------------------------------
__global__ void transpose_to_bf16(const void* __restrict__ in, int ldin, long inBatch,
                                  u16* __restrict__ out, int ldout, long outBatch,
                                  const int* __restrict__ flagp) {
    __shared__ u16 tile[32][33];
    const int isbf = flagp ? *flagp : 1;
    const long ibase = (long)blockIdx.z * inBatch;
    out += (long)blockIdx.z * outBatch;
    const int bc = blockIdx.x * 32, br = blockIdx.y * 32;
    const int tx = threadIdx.x & 31, ty = threadIdx.x >> 5;   // 256 thr
    #pragma unroll
    for (int i = 0; i < 32; i += 8)
        tile[ty + i][tx] = f2bf(loadIn(in, ibase + (long)(br + ty + i) * ldin + bc + tx, isbf));
    __syncthreads();
    #pragma unroll
    for (int i = 0; i < 32; i += 8)
        out[(long)(bc + ty + i) * ldout + br + tx] = tile[tx][ty + i];
}

// ---------------- GEMM: C[M,N] = A[M,K] @ (B^T[N,K])^T (+epilogue) ---------
// A, Bt internal bf16. 128x128 tile, BK=32, global_load_lds staging with
// pair-swizzled LDS layout: global 16B-chunk (row r, q in 0..3) lives at LDS
// chunk r*4 + (q ^ ((r>>1)&3)). Staging dest stays contiguous-by-lane;
// fragment ds_read_b128: each quarter-wave hits 8 bank-slots x2 = free.
// MODE: 0 qkv +bias(raw)->bf16        1 sc *scale->bf16
//       2 pv  plain->bf16             3 proj +bias(raw)+res(raw)->bf16
//       4 fc  +bias(raw),gelu->bf16   5 fc2 +bias(raw)+res(bf16)->flag dtype
// CAUSAL: 0 none, 1 skip blocks with n0>m0 (scores), 2 clamp K to m0+128 (pv)
template <int MODE, int CAUSAL>
__global__ __launch_bounds__(256) void gemm128(
        const u16* __restrict__ A, int lda, long aBatch,
        const u16* __restrict__ Bt, int ldb, long bBatch,
        const void* __restrict__ bias,
        void* __restrict__ Cv, int ldc, long cBatch,
        const void* __restrict__ res,
        float scale, const int* __restrict__ flagp, int K) {
    const int m0 = blockIdx.y * 128, n0 = blockIdx.x * 128;
    if (CAUSAL == 1 && n0 > m0) return;            // fully-masked score block
    __shared__ __align__(16) u16 sA[128 * 32];     // 8 KB each, pair-swizzled
    __shared__ __align__(16) u16 sB[128 * 32];
    const int bz = blockIdx.z;
    A  += (long)bz * aBatch + (long)m0 * lda;
    Bt += (long)bz * bBatch + (long)n0 * ldb;
    const int tid = threadIdx.x;
    const int wave = tid >> 6, lane = tid & 63;
    const int quad = lane >> 4, l16 = lane & 15;
    const int wr = (wave >> 1) * 64, wc = (wave & 1) * 64;

    // staging: 512 chunks/tile; thread owns LDS chunks c0, c0+256.
    // source for chunk c: row r = c>>2, col-chunk q = (c&3) ^ ((r>>1)&3).
    // second chunk (r+64) has same q: (r>>1)&3 invariant under +64 and k-step.
    const int c0 = wave * 64 + lane;
    const int r0 = c0 >> 2;
    const int qs = (c0 & 3) ^ ((r0 >> 1) & 3);
    const u16* ag = A  + (long)r0 * lda + qs * 8;
    const u16* bg = Bt + (long)r0 * ldb + qs * 8;
    u16* sAd = sA + c0 * 8;
    u16* sBd = sB + c0 * 8;
    const long aStep = (long)64 * lda, bStep = (long)64 * ldb;

    f32x4 acc[4][4];
    #pragma unroll
    for (int i = 0; i < 4; i++)
        #pragma unroll
        for (int j = 0; j < 4; j++)
            acc[i][j] = f32x4{0.f, 0.f, 0.f, 0.f};

    int Keff = K;
    if (CAUSAL == 2) Keff = min(K, m0 + 128);      // probs are 0 past diagonal

    // fragment read chunk: row ra=wr+16i+l16 -> (ra>>1)&3 == (l16>>1)&3
    const int qa = quad ^ ((l16 >> 1) & 3);

    for (int k0 = 0; k0 < Keff; k0 += 32) {
        __syncthreads();                           // prior iter's LDS reads done
        GLOAD_LDS16(ag + k0,         sAd);
        GLOAD_LDS16(ag + k0 + aStep, sAd + 2048);
        GLOAD_LDS16(bg + k0,         sBd);
        GLOAD_LDS16(bg + k0 + bStep, sBd + 2048);
        __syncthreads();                           // staging landed
        bf16x8 af[4], bfv[4];
        #pragma unroll
        for (int i = 0; i < 4; i++) {
            af[i]  = *reinterpret_cast<const bf16x8*>(&sA[(wr + 16 * i + l16) * 32 + qa * 8]);
            bfv[i] = *reinterpret_cast<const bf16x8*>(&sB[(wc + 16 * i + l16) * 32 + qa * 8]);
        }
        #pragma unroll
        for (int i = 0; i < 4; i++)
            #pragma unroll
            for (int j = 0; j < 4; j++)
                acc[i][j] = __builtin_amdgcn_mfma_f32_16x16x32_bf16(
                    af[i], bfv[j], acc[i][j], 0, 0, 0);
    }

    const int isbf = (MODE == 0 || MODE == 3 || MODE == 4 || MODE == 5) ? *flagp : 1;
    #pragma unroll
    for (int i = 0; i < 4; i++) {
        #pragma unroll
        for (int j = 0; j < 4; j++) {
            #pragma unroll
            for (int r = 0; r < 4; r++) {
                const int row = m0 + wr + 16 * i + quad * 4 + r;
                const int col = n0 + wc + 16 * j + l16;
                const long idx = (long)bz * cBatch + (long)row * ldc + col;
                float v = acc[i][j][r];
                if (MODE == 1) {
                    reinterpret_cast<u16*>(Cv)[idx] = f2bf(v * scale);
                } else {
                    if (MODE != 2) v += loadIn(bias, col, isbf);
                    if (MODE == 4) v = gelu_fast(v);
                    if (MODE == 3) v += loadIn(res, (long)row * ldc + col, isbf);
                    if (MODE == 5) v += bf2f(((const u16*)res)[(long)row * ldc + col]);
                    if (MODE == 5 && !isbf)
                        reinterpret_cast<float*>(Cv)[idx] = v;
                    else
                        reinterpret_cast<u16*>(Cv)[idx] = f2bf(v);
                }
            }
        }
    }
}

// ---------------- causal softmax: bf16 scores -> bf16 probs ----------------
__global__ void softmax_causal(const u16* __restrict__ S, u16* __restrict__ P) {
    const long row = blockIdx.x;
    const int t = (int)(row & 2047);
    const u16* sr = S + row * 2048;
    u16* pr = P + row * 2048;
    const int tid = threadIdx.x;
    float v[8];
    float mx = -INFINITY;
    #pragma unroll
    for (int i = 0; i < 8; i++) {
        int s = tid * 8 + i;
        float x = bf2f(sr[s]);
        v[i] = (s <= t) ? x : -INFINITY;
        mx = fmaxf(mx, v[i]);
    }
    mx = blockReduce<true>(mx);
    float sum = 0.f;
    #pragma unroll
    for (int i = 0; i < 8; i++) {
        int s = tid * 8 + i;
        float e = (s <= t) ? __expf(v[i] - mx) : 0.0f;
        v[i] = e;
        sum += e;
    }
    sum = blockReduce<false>(sum);
    float inv = 1.0f / sum;
    #pragma unroll
    for (int i = 0; i < 8; i++)
        pr[tid * 8 + i] = f2bf(v[i] * inv);
}

// ---------------------------------------------------------------------------
extern "C" void kernel_launch(void* const* d_in, const int* in_sizes, int n_in,
                              void* d_out, int out_size, void* d_ws, size_t ws_size,
                              hipStream_t stream) {
    const void* x      = d_in[0];
    const void* w_attn = d_in[1];
    const void* b_attn = d_in[2];
    const void* w_proj = d_in[3];
    const void* b_proj = d_in[4];
    const void* ln1_g  = d_in[5];
    const void* ln1_b  = d_in[6];
    const void* ln2_g  = d_in[7];
    const void* ln2_b  = d_in[8];
    const void* w_fc   = d_in[9];
    const void* b_fc   = d_in[10];
    const void* w_fc2  = d_in[11];
    const void* b_fc2  = d_in[12];

    // workspace layout (176.16 MB + flag)
    char* ws = (char*)d_ws;
    u16*   hbuf   = (u16*)(ws);                      // 16.78 MB: h -> y -> h2
    u16*   qkv    = (u16*)(ws + 16777216);           // 50.33 MB (later: probs+x1)
    u16*   S      = (u16*)(ws + 67108864);           // 33.5 MB bf16 scores (later: g1)
    u16*   wattnT = (u16*)(ws + 134217728);          // 25.17 MB of w^T
    u16*   wprojT = wattnT + 3072 * 1024;
    u16*   wfcT   = wprojT + 1024 * 1024;
    u16*   wfc2T  = wfcT + 4096 * 1024;
    u16*   vT     = wfc2T + 1024 * 4096;             // 16.78 MB
    int*   flag   = (int*)(ws + 176160768);
    u16*   probs  = qkv;                   // reuses qkv region after scores
    u16*   x1     = qkv + 16777216;

    detect_dtype<<<1, 256, 0, stream>>>((const u16*)x, flag);

    // weight transposes (raw dtype -> bf16)
    transpose_to_bf16<<<dim3(96, 32, 1),  256, 0, stream>>>(w_attn, 3072, 0, wattnT, 1024, 0, flag);
    transpose_to_bf16<<<dim3(32, 32, 1),  256, 0, stream>>>(w_proj, 1024, 0, wprojT, 1024, 0, flag);
    transpose_to_bf16<<<dim3(128, 32, 1), 256, 0, stream>>>(w_fc,   4096, 0, wfcT,   1024, 0, flag);
    transpose_to_bf16<<<dim3(32, 128, 1), 256, 0, stream>>>(w_fc2,  1024, 0, wfc2T,  4096, 0, flag);

    // h = LN1(x)
    ln_kernel<true><<<8192, 256, 0, stream>>>(x, ln1_g, ln1_b, hbuf, flag);

    // qkv = h @ w_attn + b_attn       [8192, 3072]
    gemm128<0, 0><<<dim3(24, 64, 1), 256, 0, stream>>>(
        hbuf, 1024, 0, wattnT, 1024, 0, b_attn, qkv, 3072, 0, nullptr, 0.f, flag, 1024);

    // vT[b] = V[b]^T                   [1024, 2048] x4
    transpose_to_bf16<<<dim3(32, 64, 4), 256, 0, stream>>>(
        qkv + 2048, 3072, (long)2048 * 3072, vT, 2048, (long)1024 * 2048, nullptr);

    // S[b] = 0.125 * q[b] @ k[b]^T    [2048, 2048] bf16 x4, upper blocks skipped
    gemm128<1, 1><<<dim3(16, 16, 4), 256, 0, stream>>>(
        qkv, 3072, (long)2048 * 3072, qkv + 1024, 3072, (long)2048 * 3072,
        nullptr, S, 2048, (long)2048 * 2048, nullptr, 0.125f, flag, 1024);

    // probs = causal softmax(S)
    softmax_causal<<<8192, 256, 0, stream>>>(S, probs);

    // y[b] = P[b] @ V[b]              [2048, 1024] x4, K clamped to diagonal
    gemm128<2, 2><<<dim3(8, 16, 4), 256, 0, stream>>>(
        probs, 2048, (long)2048 * 2048, vT, 2048, (long)1024 * 2048,
        nullptr, hbuf, 1024, (long)2048 * 1024, nullptr, 0.f, flag, 2048);

    // x1 = x + y @ w_proj + b_proj    (bf16, in ws)
    gemm128<3, 0><<<dim3(8, 64, 1), 256, 0, stream>>>(
        hbuf, 1024, 0, wprojT, 1024, 0, b_proj, x1, 1024, 0, x, 0.f, flag, 1024);

    // h2 = LN2(x1) -> hbuf
    ln_kernel<false><<<8192, 256, 0, stream>>>(x1, ln2_g, ln2_b, hbuf, flag);

    // g1 = gelu(h2 @ w_fc + b_fc)     [8192, 4096] bf16 in S region
    gemm128<4, 0><<<dim3(32, 64, 1), 256, 0, stream>>>(
        hbuf, 1024, 0, wfcT, 1024, 0, b_fc, S, 4096, 0, nullptr, 0.f, flag, 1024);

    // out = x1 + g1 @ w_fc2 + b_fc2   (written in detected dtype)
    gemm128<5, 0><<<dim3(8, 64, 1), 256, 0, stream>>>(
        S, 4096, 0, wfc2T, 4096, 0, b_fc2, d_out, 1024, 0, x1, 0.f, flag, 4096);
}

// Round 6
// 680.934 us; speedup vs baseline: 1.0168x; 1.0168x over previous
//
#include <hip/hip_runtime.h>
#include <math.h>

// ---------------------------------------------------------------------------
// GPT transformer block, internal bf16 compute / fp32 accumulate.
// B=4, T=2048, D=1024 (8192 rows), 3D=3072, 4D=4096.
// Round 6: TM=64 tile variant (64x128, 2x overlap) for the concurrency-starved
// dispatches (scores / pv / proj had only ~2 active blocks/CU -> per-iter
// vmcnt drain unhidden). FC/qkv/fc2 stay TM=128 (at m97-structure rate).
// Softmax: 16B vector IO + causal chunk skip (PV only needs zeros to t|63).
// ---------------------------------------------------------------------------

typedef unsigned short u16;
typedef __attribute__((ext_vector_type(8))) short bf16x8;   // 8 bf16 = 4 VGPRs
typedef __attribute__((ext_vector_type(8))) unsigned short u16x8;
typedef __attribute__((ext_vector_type(4))) float f32x4;

#define DEV __device__ __forceinline__

#define GLOAD_LDS16(gp, lp)                                                     \
    __builtin_amdgcn_global_load_lds(                                           \
        (const __attribute__((address_space(1))) void*)(gp),                    \
        (__attribute__((address_space(3))) void*)(lp), 16, 0, 0)

DEV float bf2f(u16 h) {
    union { unsigned u; float f; } t; t.u = ((unsigned)h) << 16; return t.f;
}
DEV u16 f2bf(float f) {
    union { unsigned u; float f; } t; t.f = f;
    unsigned u = t.u;
    return (u16)((u + 0x7FFFu + ((u >> 16) & 1u)) >> 16);   // round-nearest-even
}
DEV float loadIn(const void* p, long i, int isbf) {
    return isbf ? bf2f(((const u16*)p)[i]) : ((const float*)p)[i];
}
// gelu(x) = 0.5x(1+tanh(u)) = x * sigmoid(2u); ~6 VALU vs libm tanhf's ~30+
DEV float gelu_fast(float x) {
    float u = 1.5957691216057308f * (x + 0.044715f * x * x * x);  // 2*sqrt(2/pi)
    return x * __builtin_amdgcn_rcpf(1.0f + __expf(-u));
}

DEV float waveSum(float v) {
    #pragma unroll
    for (int o = 32; o > 0; o >>= 1) v += __shfl_down(v, o, 64);
    return v;
}
DEV float waveMax(float v) {
    #pragma unroll
    for (int o = 32; o > 0; o >>= 1) v = fmaxf(v, __shfl_down(v, o, 64));
    return v;
}

template <bool IS_MAX>
DEV float blockReduce(float v) {
    __shared__ float tmp[5];
    __syncthreads();
    v = IS_MAX ? waveMax(v) : waveSum(v);
    int lane = threadIdx.x & 63, w = threadIdx.x >> 6;
    if (lane == 0) tmp[w] = v;
    __syncthreads();
    if (threadIdx.x == 0) {
        float r = tmp[0];
        for (int i = 1; i < 4; i++) r = IS_MAX ? fmaxf(r, tmp[i]) : (r + tmp[i]);
        tmp[4] = r;
    }
    __syncthreads();
    return tmp[4];
}

// ---------------- dtype detection (1 block) --------------------------------
__global__ void detect_dtype(const u16* __restrict__ xr, int* __restrict__ flag) {
    const int tid = threadIdx.x;           // 256
    int cnt = 0;
    #pragma unroll
    for (int i = 0; i < 16; i++) {
        unsigned u = xr[2 * (tid + 256 * i)];      // even u16 indices
        unsigned e = (u >> 7) & 0xFF;              // bf16 exponent field
        cnt += (e >= 100 && e <= 140) ? 1 : 0;     // ~always for bf16 N(0,1)
    }
    __shared__ int sh[4];
    #pragma unroll
    for (int o = 32; o > 0; o >>= 1) cnt += __shfl_down(cnt, o, 64);
    if ((tid & 63) == 0) sh[tid >> 6] = cnt;
    __syncthreads();
    if (tid == 0) flag[0] = (sh[0] + sh[1] + sh[2] + sh[3] > 2048) ? 1 : 0;
}

// ---------------- LayerNorm (D=1024, one 256-thread block per row) ---------
template <bool RAW_IN>
__global__ void ln_kernel(const void* __restrict__ x, const void* __restrict__ g,
                          const void* __restrict__ b, u16* __restrict__ out,
                          const int* __restrict__ flagp) {
    const int isbf = *flagp;
    const int inbf = RAW_IN ? isbf : 1;
    const long base = (long)blockIdx.x * 1024;
    const int tid = threadIdx.x;
    float v[4];
    #pragma unroll
    for (int j = 0; j < 4; j++) v[j] = loadIn(x, base + tid + 256 * j, inbf);
    float mu = blockReduce<false>(v[0] + v[1] + v[2] + v[3]) * (1.0f / 1024.0f);
    float d[4], sq = 0.f;
    #pragma unroll
    for (int j = 0; j < 4; j++) { d[j] = v[j] - mu; sq += d[j] * d[j]; }
    float var = blockReduce<false>(sq) * (1.0f / 1024.0f);
    float rstd = rsqrtf(var + 1e-5f);
    #pragma unroll
    for (int j = 0; j < 4; j++) {
        int c = tid + 256 * j;
        out[base + c] = f2bf(d[j] * rstd * loadIn(g, c, isbf) + loadIn(b, c, isbf));
    }
}

// ---------------- 32x32 transpose -> bf16 ----------------------------------
__global__ void transpose_to_bf16(const void* __restrict__ in, int ldin, long inBatch,
                                  u16* __restrict__ out, int ldout, long outBatch,
                                  const int* __restrict__ flagp) {
    __shared__ u16 tile[32][33];
    const int isbf = flagp ? *flagp : 1;
    const long ibase = (long)blockIdx.z * inBatch;
    out += (long)blockIdx.z * outBatch;
    const int bc = blockIdx.x * 32, br = blockIdx.y * 32;
    const int tx = threadIdx.x & 31, ty = threadIdx.x >> 5;   // 256 thr
    #pragma unroll
    for (int i = 0; i < 32; i += 8)
        tile[ty + i][tx] = f2bf(loadIn(in, ibase + (long)(br + ty + i) * ldin + bc + tx, isbf));
    __syncthreads();
    #pragma unroll
    for (int i = 0; i < 32; i += 8)
        out[(long)(bc + ty + i) * ldout + br + tx] = tile[tx][ty + i];
}

// ---------------- GEMM: C[M,N] = A[M,K] @ (B^T[N,K])^T (+epilogue) ---------
// A, Bt internal bf16. TM x 128 tile (TM in {64,128}), BK=32, global_load_lds
// staging, pair-swizzled LDS (chunk q ^ ((r>>1)&3)) -> conflict-free b128.
// 4 waves: wave-tile (TM/2) x 64, frags (TM/32) x 4.
// MODE: 0 qkv +bias(raw)->bf16        1 sc *scale->bf16
//       2 pv  plain->bf16             3 proj +bias(raw)+res(raw)->bf16
//       4 fc  +bias(raw),gelu->bf16   5 fc2 +bias(raw)+res(bf16)->flag dtype
// CAUSAL: 0 none, 1 skip blocks fully above diag, 2 clamp K to m0+TM (pv)
template <int MODE, int CAUSAL, int TM>
__global__ __launch_bounds__(256) void gemm_mf(
        const u16* __restrict__ A, int lda, long aBatch,
        const u16* __restrict__ Bt, int ldb, long bBatch,
        const void* __restrict__ bias,
        void* __restrict__ Cv, int ldc, long cBatch,
        const void* __restrict__ res,
        float scale, const int* __restrict__ flagp, int K) {
    constexpr int FI = TM / 32;                    // acc frags in m
    const int m0 = blockIdx.y * TM, n0 = blockIdx.x * 128;
    if (CAUSAL == 1 && n0 > m0 + TM - 1) return;   // fully-masked score block
    __shared__ __align__(16) u16 sA[TM * 32];      // pair-swizzled
    __shared__ __align__(16) u16 sB[128 * 32];
    const int bz = blockIdx.z;
    A  += (long)bz * aBatch + (long)m0 * lda;
    Bt += (long)bz * bBatch + (long)n0 * ldb;
    const int tid = threadIdx.x;
    const int wave = tid >> 6, lane = tid & 63;
    const int quad = lane >> 4, l16 = lane & 15;
    const int wr = (wave >> 1) * (TM / 2), wc = (wave & 1) * 64;

    // staging: chunk c -> row r=c>>2, stored q = (c&3); source q = (c&3)^((r>>1)&3)
    const int c0 = tid;
    const int r0 = c0 >> 2;
    const int qs = (c0 & 3) ^ ((r0 >> 1) & 3);
    const u16* ag = A  + (long)r0 * lda + qs * 8;
    const u16* bg = Bt + (long)r0 * ldb + qs * 8;
    u16* sAd = sA + c0 * 8;
    u16* sBd = sB + c0 * 8;
    const long aStep = (long)64 * lda, bStep = (long)64 * ldb;

    f32x4 acc[FI][4];
    #pragma unroll
    for (int i = 0; i < FI; i++)
        #pragma unroll
        for (int j = 0; j < 4; j++)
            acc[i][j] = f32x4{0.f, 0.f, 0.f, 0.f};

    int Keff = K;
    if (CAUSAL == 2) Keff = min(K, m0 + TM);       // probs are 0 past diagonal

    const int qa = quad ^ ((l16 >> 1) & 3);        // frag-read swizzled chunk

    for (int k0 = 0; k0 < Keff; k0 += 32) {
        __syncthreads();                           // prior iter's LDS reads done
        GLOAD_LDS16(ag + k0, sAd);
        if (TM == 128) GLOAD_LDS16(ag + k0 + aStep, sAd + 2048);
        GLOAD_LDS16(bg + k0,         sBd);
        GLOAD_LDS16(bg + k0 + bStep, sBd + 2048);
        __syncthreads();                           // staging landed
        bf16x8 af[FI], bfv[4];
        #pragma unroll
        for (int i = 0; i < FI; i++)
            af[i]  = *reinterpret_cast<const bf16x8*>(&sA[(wr + 16 * i + l16) * 32 + qa * 8]);
        #pragma unroll
        for (int j = 0; j < 4; j++)
            bfv[j] = *reinterpret_cast<const bf16x8*>(&sB[(wc + 16 * j + l16) * 32 + qa * 8]);
        #pragma unroll
        for (int i = 0; i < FI; i++)
            #pragma unroll
            for (int j = 0; j < 4; j++)
                acc[i][j] = __builtin_amdgcn_mfma_f32_16x16x32_bf16(
                    af[i], bfv[j], acc[i][j], 0, 0, 0);
    }

    const int isbf = (MODE == 0 || MODE == 3 || MODE == 4 || MODE == 5) ? *flagp : 1;
    #pragma unroll
    for (int i = 0; i < FI; i++) {
        #pragma unroll
        for (int j = 0; j < 4; j++) {
            #pragma unroll
            for (int r = 0; r < 4; r++) {
                const int row = m0 + wr + 16 * i + quad * 4 + r;
                const int col = n0 + wc + 16 * j + l16;
                const long idx = (long)bz * cBatch + (long)row * ldc + col;
                float v = acc[i][j][r];
                if (MODE == 1) {
                    reinterpret_cast<u16*>(Cv)[idx] = f2bf(v * scale);
                } else {
                    if (MODE != 2) v += loadIn(bias, col, isbf);
                    if (MODE == 4) v = gelu_fast(v);
                    if (MODE == 3) v += loadIn(res, (long)row * ldc + col, isbf);
                    if (MODE == 5) v += bf2f(((const u16*)res)[(long)row * ldc + col]);
                    if (MODE == 5 && !isbf)
                        reinterpret_cast<float*>(Cv)[idx] = v;
                    else
                        reinterpret_cast<u16*>(Cv)[idx] = f2bf(v);
                }
            }
        }
    }
}

// ---------------- causal softmax: bf16 scores -> bf16 probs ----------------
// Row r: valid cols <= t=r&2047. PV (Keff = m0+64 clamp) only ever reads cols
// < (t|63)+1, so stores beyond t|63 are skipped; loads beyond t skipped.
__global__ void softmax_causal(const u16* __restrict__ S, u16* __restrict__ P) {
    const long row = blockIdx.x;
    const int t = (int)(row & 2047);
    const u16* sr = S + row * 2048;
    u16* pr = P + row * 2048;
    const int tid = threadIdx.x;
    const int s0 = tid * 8;
    float v[8];
    float mx = -INFINITY;
    if (s0 <= t) {
        u16x8 raw = *reinterpret_cast<const u16x8*>(sr + s0);
        #pragma unroll
        for (int i = 0; i < 8; i++) {
            float x = bf2f(raw[i]);
            v[i] = (s0 + i <= t) ? x : -INFINITY;
            mx = fmaxf(mx, v[i]);
        }
    } else {
        #pragma unroll
        for (int i = 0; i < 8; i++) v[i] = -INFINITY;
    }
    mx = blockReduce<true>(mx);
    float sum = 0.f;
    #pragma unroll
    for (int i = 0; i < 8; i++) {
        float e = (v[i] == -INFINITY) ? 0.0f : __expf(v[i] - mx);
        v[i] = e;
        sum += e;
    }
    sum = blockReduce<false>(sum);
    float inv = 1.0f / sum;
    if (s0 <= (t | 63)) {
        u16x8 o;
        #pragma unroll
        for (int i = 0; i < 8; i++) o[i] = f2bf(v[i] * inv);
        *reinterpret_cast<u16x8*>(pr + s0) = o;
    }
}

// ---------------------------------------------------------------------------
extern "C" void kernel_launch(void* const* d_in, const int* in_sizes, int n_in,
                              void* d_out, int out_size, void* d_ws, size_t ws_size,
                              hipStream_t stream) {
    const void* x      = d_in[0];
    const void* w_attn = d_in[1];
    const void* b_attn = d_in[2];
    const void* w_proj = d_in[3];
    const void* b_proj = d_in[4];
    const void* ln1_g  = d_in[5];
    const void* ln1_b  = d_in[6];
    const void* ln2_g  = d_in[7];
    const void* ln2_b  = d_in[8];
    const void* w_fc   = d_in[9];
    const void* b_fc   = d_in[10];
    const void* w_fc2  = d_in[11];
    const void* b_fc2  = d_in[12];

    // workspace layout (176.16 MB + flag)
    char* ws = (char*)d_ws;
    u16*   hbuf   = (u16*)(ws);                      // 16.78 MB: h -> y -> h2
    u16*   qkv    = (u16*)(ws + 16777216);           // 50.33 MB (later: probs+x1)
    u16*   S      = (u16*)(ws + 67108864);           // 33.5 MB bf16 scores (later: g1)
    u16*   wattnT = (u16*)(ws + 134217728);          // 25.17 MB of w^T
    u16*   wprojT = wattnT + 3072 * 1024;
    u16*   wfcT   = wprojT + 1024 * 1024;
    u16*   wfc2T  = wfcT + 4096 * 1024;
    u16*   vT     = wfc2T + 1024 * 4096;             // 16.78 MB
    int*   flag   = (int*)(ws + 176160768);
    u16*   probs  = qkv;                   // reuses qkv region after scores
    u16*   x1     = qkv + 16777216;

    detect_dtype<<<1, 256, 0, stream>>>((const u16*)x, flag);

    // weight transposes (raw dtype -> bf16)
    transpose_to_bf16<<<dim3(96, 32, 1),  256, 0, stream>>>(w_attn, 3072, 0, wattnT, 1024, 0, flag);
    transpose_to_bf16<<<dim3(32, 32, 1),  256, 0, stream>>>(w_proj, 1024, 0, wprojT, 1024, 0, flag);
    transpose_to_bf16<<<dim3(128, 32, 1), 256, 0, stream>>>(w_fc,   4096, 0, wfcT,   1024, 0, flag);
    transpose_to_bf16<<<dim3(32, 128, 1), 256, 0, stream>>>(w_fc2,  1024, 0, wfc2T,  4096, 0, flag);

    // h = LN1(x)
    ln_kernel<true><<<8192, 256, 0, stream>>>(x, ln1_g, ln1_b, hbuf, flag);

    // qkv = h @ w_attn + b_attn       [8192, 3072]   TM=128
    gemm_mf<0, 0, 128><<<dim3(24, 64, 1), 256, 0, stream>>>(
        hbuf, 1024, 0, wattnT, 1024, 0, b_attn, qkv, 3072, 0, nullptr, 0.f, flag, 1024);

    // vT[b] = V[b]^T                   [1024, 2048] x4
    transpose_to_bf16<<<dim3(32, 64, 4), 256, 0, stream>>>(
        qkv + 2048, 3072, (long)2048 * 3072, vT, 2048, (long)1024 * 2048, nullptr);

    // S[b] = 0.125 * q[b] @ k[b]^T    [2048, 2048] bf16 x4   TM=64, lower-tri
    gemm_mf<1, 1, 64><<<dim3(16, 32, 4), 256, 0, stream>>>(
        qkv, 3072, (long)2048 * 3072, qkv + 1024, 3072, (long)2048 * 3072,
        nullptr, S, 2048, (long)2048 * 2048, nullptr, 0.125f, flag, 1024);

    // probs = causal softmax(S)
    softmax_causal<<<8192, 256, 0, stream>>>(S, probs);

    // y[b] = P[b] @ V[b]              [2048, 1024] x4   TM=64, K clamped
    gemm_mf<2, 2, 64><<<dim3(8, 32, 4), 256, 0, stream>>>(
        probs, 2048, (long)2048 * 2048, vT, 2048, (long)1024 * 2048,
        nullptr, hbuf, 1024, (long)2048 * 1024, nullptr, 0.f, flag, 2048);

    // x1 = x + y @ w_proj + b_proj    (bf16, in ws)   TM=64
    gemm_mf<3, 0, 64><<<dim3(8, 128, 1), 256, 0, stream>>>(
        hbuf, 1024, 0, wprojT, 1024, 0, b_proj, x1, 1024, 0, x, 0.f, flag, 1024);

    // h2 = LN2(x1) -> hbuf
    ln_kernel<false><<<8192, 256, 0, stream>>>(x1, ln2_g, ln2_b, hbuf, flag);

    // g1 = gelu(h2 @ w_fc + b_fc)     [8192, 4096] bf16 in S region   TM=128
    gemm_mf<4, 0, 128><<<dim3(32, 64, 1), 256, 0, stream>>>(
        hbuf, 1024, 0, wfcT, 1024, 0, b_fc, S, 4096, 0, nullptr, 0.f, flag, 1024);

    // out = x1 + g1 @ w_fc2 + b_fc2   (written in detected dtype)   TM=128
    gemm_mf<5, 0, 128><<<dim3(8, 64, 1), 256, 0, stream>>>(
        S, 4096, 0, wfc2T, 4096, 0, b_fc2, d_out, 1024, 0, x1, 0.f, flag, 4096);
}